// Round 1
// baseline (452.155 us; speedup 1.0000x reference)
//
#include <hip/hip_runtime.h>
#include <hip/hip_bf16.h>
#include <stdint.h>
#include <string.h>

#define D_MODEL 768
#define H_HEADS 12
#define HD_ 64
#define N_QKV 2304

typedef __bf16 bf16x8 __attribute__((ext_vector_type(8)));
typedef float f32x4 __attribute__((ext_vector_type(4)));

__device__ __forceinline__ void gload16(const void* gsrc, void* ldst) {
  __builtin_amdgcn_global_load_lds(
      (__attribute__((address_space(1))) void*)gsrc,
      (__attribute__((address_space(3))) void*)ldst, 16, 0, 0);
}

__device__ __forceinline__ unsigned short f2bfbits(float f) {
  union { float f; unsigned u; } x; x.f = f;
  unsigned r = x.u + 0x7fffu + ((x.u >> 16) & 1u);
  return (unsigned short)(r >> 16);
}
__device__ __forceinline__ float bfbits2f(unsigned short b) {
  union { unsigned u; float f; } x; x.u = ((unsigned)b) << 16;
  return x.f;
}

// ---------------- weight transpose + fp32->bf16 ----------------
// in: R x C fp32 row-major; out: C x R bf16 row-major (i.e. B^T with K contiguous)
__global__ void transpose_w(const float* __restrict__ in, unsigned short* __restrict__ out,
                            int R, int C) {
  __shared__ float tile[32][33];
  int c0 = blockIdx.x * 32, r0 = blockIdx.y * 32;
  int tx = threadIdx.x, ty = threadIdx.y;
#pragma unroll
  for (int i = 0; i < 32; i += 8)
    tile[ty + i][tx] = in[(size_t)(r0 + ty + i) * C + c0 + tx];
  __syncthreads();
#pragma unroll
  for (int i = 0; i < 32; i += 8)
    out[(size_t)(c0 + ty + i) * R + r0 + tx] = f2bfbits(tile[tx][ty + i]);
}

// ---------------- layernorm -> bf16 ----------------
__global__ void ln_bf16(const float* __restrict__ x, const float* __restrict__ g,
                        const float* __restrict__ be, unsigned short* __restrict__ out) {
  int row = blockIdx.x;
  const float* xr = x + (size_t)row * D_MODEL;
  int t = threadIdx.x;
  float v0 = xr[t], v1 = xr[t + 256], v2 = xr[t + 512];
  float s = v0 + v1 + v2;
  float s2 = v0 * v0 + v1 * v1 + v2 * v2;
#pragma unroll
  for (int off = 32; off > 0; off >>= 1) {
    s += __shfl_down(s, off, 64);
    s2 += __shfl_down(s2, off, 64);
  }
  __shared__ float red[8];
  int w = t >> 6, lane = t & 63;
  if (lane == 0) { red[w] = s; red[w + 4] = s2; }
  __syncthreads();
  if (t == 0) {
    float a = red[0] + red[1] + red[2] + red[3];
    float b = red[4] + red[5] + red[6] + red[7];
    red[0] = a * (1.0f / 768.0f);
    red[4] = b * (1.0f / 768.0f);
  }
  __syncthreads();
  float mu = red[0];
  float var = red[4] - mu * mu;
  float rs = rsqrtf(var + 1e-6f);
  unsigned short* orow = out + (size_t)row * D_MODEL;
  orow[t]       = f2bfbits((v0 - mu) * rs * g[t]       + be[t]);
  orow[t + 256] = f2bfbits((v1 - mu) * rs * g[t + 256] + be[t + 256]);
  orow[t + 512] = f2bfbits((v2 - mu) * rs * g[t + 512] + be[t + 512]);
}

// ---------------- m97-style bf16 MFMA GEMM, B^T input ----------------
// EPI 0: out = bf16(acc + bias)        (QKV)
// EPI 1: out = f32(acc + bias + res)   (Wo, FC2)
// EPI 2: out = bf16(gelu(acc + bias))  (FC1)
template <int EPI>
__global__ void gemm_bt(const unsigned short* __restrict__ A,
                        const unsigned short* __restrict__ Bt,
                        const float* __restrict__ bias,
                        const float* __restrict__ res,
                        void* __restrict__ outv,
                        int M, int N, int K) {
  __shared__ unsigned short lA[128 * 32];
  __shared__ unsigned short lB[128 * 32];
  int tid = threadIdx.x;
  int w = tid >> 6, lane = tid & 63;
  int m0 = blockIdx.y * 128, n0 = blockIdx.x * 128;
  int wm = (w >> 1) * 64, wn = (w & 1) * 64;
  f32x4 acc[4][4];
#pragma unroll
  for (int i = 0; i < 4; i++)
#pragma unroll
    for (int j = 0; j < 4; j++) acc[i][j] = (f32x4){0.f, 0.f, 0.f, 0.f};

  int srow = tid >> 2, scol = (tid & 3) * 8;
  const unsigned short* gA0 = A + (size_t)(m0 + srow) * K + scol;
  const unsigned short* gB0 = Bt + (size_t)(n0 + srow) * K + scol;
  char* lA0 = (char*)lA + tid * 16;
  char* lB0 = (char*)lB + tid * 16;
  int fm = lane & 15, fk = (lane >> 4) * 8;

  for (int k0 = 0; k0 < K; k0 += 32) {
    __syncthreads();
    gload16(gA0 + k0, lA0);
    gload16(gA0 + (size_t)64 * K + k0, lA0 + 4096);
    gload16(gB0 + k0, lB0);
    gload16(gB0 + (size_t)64 * K + k0, lB0 + 4096);
    __syncthreads();
    bf16x8 af[4], bfr[4];
#pragma unroll
    for (int i = 0; i < 4; i++)
      af[i] = *(const bf16x8*)&lA[(wm + i * 16 + fm) * 32 + fk];
#pragma unroll
    for (int j = 0; j < 4; j++)
      bfr[j] = *(const bf16x8*)&lB[(wn + j * 16 + fm) * 32 + fk];
#pragma unroll
    for (int i = 0; i < 4; i++)
#pragma unroll
      for (int j = 0; j < 4; j++)
        acc[i][j] = __builtin_amdgcn_mfma_f32_16x16x32_bf16(af[i], bfr[j], acc[i][j], 0, 0, 0);
  }

  int er = (lane >> 4) * 4, ec = lane & 15;
#pragma unroll
  for (int i = 0; i < 4; i++) {
#pragma unroll
    for (int j = 0; j < 4; j++) {
      int n = n0 + wn + j * 16 + ec;
      float bv = bias[n];
#pragma unroll
      for (int r = 0; r < 4; r++) {
        int m = m0 + wm + i * 16 + er + r;
        float v = acc[i][j][r] + bv;
        if (EPI == 1) {
          v += res[(size_t)m * N + n];
          ((float*)outv)[(size_t)m * N + n] = v;
        } else {
          if (EPI == 2) v = 0.5f * v * (1.0f + erff(v * 0.70710678118f));
          ((unsigned short*)outv)[(size_t)m * N + n] = f2bfbits(v);
        }
      }
    }
  }
}

// ---------------- ragged flash attention ----------------
// grid: B * H * (S_MAX/64); block 256 (4 waves), wave w handles q rows [qc*64+w*16, +16)
__global__ void attn_flash(const unsigned short* __restrict__ qkv,
                           const int* __restrict__ cu,
                           unsigned short* __restrict__ out) {
  int qc = blockIdx.x & 15;
  int h = (blockIdx.x >> 4) % H_HEADS;
  int b = blockIdx.x / (16 * H_HEADS);
  int tok0 = cu[b];
  int len = cu[b + 1] - tok0;
  if (qc * 64 >= len) return;

  __shared__ unsigned short lK[32 * 64];   // [key][d]
  __shared__ unsigned short lVT[64 * 32];  // [d][key]
  __shared__ unsigned short lP[4 * 16 * 32];

  int tid = threadIdx.x, w = tid >> 6, lane = tid & 63;
  int fm = lane & 15, fg = lane >> 4;

  int qrow = tok0 + qc * 64 + w * 16 + fm;
  const unsigned short* qp = qkv + (size_t)qrow * N_QKV + h * HD_ + fg * 8;
  bf16x8 qf0 = *(const bf16x8*)qp;
  bf16x8 qf1 = *(const bf16x8*)(qp + 32);

  f32x4 Oacc[4];
#pragma unroll
  for (int d = 0; d < 4; d++) Oacc[d] = (f32x4){0.f, 0.f, 0.f, 0.f};
  float mrow[4] = {-1e30f, -1e30f, -1e30f, -1e30f};
  float lrow[4] = {0.f, 0.f, 0.f, 0.f};

  int skey = tid >> 3, sd = (tid & 7) * 8;
  const unsigned short* kg = qkv + (size_t)(tok0 + skey) * N_QKV + D_MODEL + h * HD_ + sd;
  const unsigned short* vg = qkv + (size_t)(tok0 + skey) * N_QKV + 2 * D_MODEL + h * HD_ + sd;
  unsigned short* lPw = lP + w * 512;

  for (int kt = 0; kt < len; kt += 32) {
    __syncthreads();
    gload16(kg + (size_t)kt * N_QKV, (char*)lK + tid * 16);
    uint4 vv = *(const uint4*)(vg + (size_t)kt * N_QKV);
    const unsigned short* vs = (const unsigned short*)&vv;
#pragma unroll
    for (int j = 0; j < 8; j++) lVT[(sd + j) * 32 + skey] = vs[j];
    __syncthreads();

    f32x4 s[2];
    s[0] = (f32x4){0.f, 0.f, 0.f, 0.f};
    s[1] = (f32x4){0.f, 0.f, 0.f, 0.f};
#pragma unroll
    for (int t = 0; t < 2; t++) {
      bf16x8 kf0 = *(const bf16x8*)&lK[(t * 16 + fm) * 64 + fg * 8];
      bf16x8 kf1 = *(const bf16x8*)&lK[(t * 16 + fm) * 64 + 32 + fg * 8];
      s[t] = __builtin_amdgcn_mfma_f32_16x16x32_bf16(qf0, kf0, s[t], 0, 0, 0);
      s[t] = __builtin_amdgcn_mfma_f32_16x16x32_bf16(qf1, kf1, s[t], 0, 0, 0);
    }
    s[0] *= 0.125f;
    s[1] *= 0.125f;

    float anew[4], mnew[4], rsum[4];
#pragma unroll
    for (int r = 0; r < 4; r++) {
      float mx = fmaxf(s[0][r], s[1][r]);
#pragma unroll
      for (int off = 1; off < 16; off <<= 1) mx = fmaxf(mx, __shfl_xor(mx, off, 64));
      mnew[r] = fmaxf(mrow[r], mx);
      anew[r] = __expf(mrow[r] - mnew[r]);
      rsum[r] = 0.f;
    }
#pragma unroll
    for (int t = 0; t < 2; t++)
#pragma unroll
      for (int r = 0; r < 4; r++) {
        float p = __expf(s[t][r] - mnew[r]);
        unsigned short pb = f2bfbits(p);
        lPw[(fg * 4 + r) * 32 + t * 16 + fm] = pb;
        rsum[r] += bfbits2f(pb);
      }
#pragma unroll
    for (int r = 0; r < 4; r++) {
#pragma unroll
      for (int off = 1; off < 16; off <<= 1) rsum[r] += __shfl_xor(rsum[r], off, 64);
      lrow[r] = lrow[r] * anew[r] + rsum[r];
      mrow[r] = mnew[r];
    }
#pragma unroll
    for (int d = 0; d < 4; d++) {
      Oacc[d][0] *= anew[0];
      Oacc[d][1] *= anew[1];
      Oacc[d][2] *= anew[2];
      Oacc[d][3] *= anew[3];
    }
    __asm__ __volatile__("s_waitcnt lgkmcnt(0)" ::: "memory");
    bf16x8 pf = *(const bf16x8*)&lPw[fm * 32 + fg * 8];
#pragma unroll
    for (int d = 0; d < 4; d++) {
      bf16x8 vf = *(const bf16x8*)&lVT[(d * 16 + fm) * 32 + fg * 8];
      Oacc[d] = __builtin_amdgcn_mfma_f32_16x16x32_bf16(pf, vf, Oacc[d], 0, 0, 0);
    }
  }

#pragma unroll
  for (int r = 0; r < 4; r++) {
    float inv = 1.0f / lrow[r];
    int m = tok0 + qc * 64 + w * 16 + fg * 4 + r;
#pragma unroll
    for (int d = 0; d < 4; d++)
      out[(size_t)m * D_MODEL + h * HD_ + d * 16 + fm] = f2bfbits(Oacc[d][r] * inv);
  }
}

extern "C" void kernel_launch(void* const* d_in, const int* in_sizes, int n_in,
                              void* d_out, int out_size, void* d_ws, size_t ws_size,
                              hipStream_t stream) {
  const float* x    = (const float*)d_in[0];
  const int* cu     = (const int*)d_in[1];
  const float* g1   = (const float*)d_in[2];
  const float* be1  = (const float*)d_in[3];
  const float* Wqkv = (const float*)d_in[4];
  const float* bqkv = (const float*)d_in[5];
  const float* Wo   = (const float*)d_in[6];
  const float* bo   = (const float*)d_in[7];
  const float* g2   = (const float*)d_in[8];
  const float* be2  = (const float*)d_in[9];
  const float* W1   = (const float*)d_in[10];
  const float* bfc1 = (const float*)d_in[11];
  const float* W2   = (const float*)d_in[12];
  const float* bfc2 = (const float*)d_in[13];
  float* out = (float*)d_out;
  int M = in_sizes[0] / D_MODEL;  // 6144

  // workspace layout (bytes): weightsT bf16 (14.16M) | bufA bf16 (9.44M) |
  // x1 f32 (18.87M) | qkv/m bf16 (37.75M overlap region) = 80.2 MB total
  unsigned short* WqkvT = (unsigned short*)d_ws;                     // 2304x768
  unsigned short* WoT   = WqkvT + 2304 * 768;                        // 768x768
  unsigned short* W1T   = WoT + 768 * 768;                           // 3072x768
  unsigned short* W2T   = W1T + 3072 * 768;                          // 768x3072
  unsigned short* bufA  = W2T + 768 * 3072;                          // M x 768 bf16
  float* x1             = (float*)(bufA + (size_t)M * D_MODEL);      // M x 768 f32
  unsigned short* qkvb  = (unsigned short*)(x1 + (size_t)M * D_MODEL); // M x 2304 bf16 / M x 3072 bf16 (m)

  dim3 b32(32, 8);
  transpose_w<<<dim3(2304 / 32, 768 / 32), b32, 0, stream>>>(Wqkv, WqkvT, 768, 2304);
  transpose_w<<<dim3(768 / 32, 768 / 32), b32, 0, stream>>>(Wo, WoT, 768, 768);
  transpose_w<<<dim3(3072 / 32, 768 / 32), b32, 0, stream>>>(W1, W1T, 768, 3072);
  transpose_w<<<dim3(768 / 32, 3072 / 32), b32, 0, stream>>>(W2, W2T, 3072, 768);

  ln_bf16<<<M, 256, 0, stream>>>(x, g1, be1, bufA);
  gemm_bt<0><<<dim3(2304 / 128, M / 128), 256, 0, stream>>>(bufA, WqkvT, bqkv, nullptr, qkvb, M, 2304, 768);
  attn_flash<<<8 * H_HEADS * 16, 256, 0, stream>>>(qkvb, cu, bufA);
  gemm_bt<1><<<dim3(768 / 128, M / 128), 256, 0, stream>>>(bufA, WoT, bo, x, x1, M, 768, 768);
  ln_bf16<<<M, 256, 0, stream>>>(x1, g2, be2, bufA);
  gemm_bt<2><<<dim3(3072 / 128, M / 128), 256, 0, stream>>>(bufA, W1T, bfc1, nullptr, qkvb, M, 3072, 768);
  gemm_bt<1><<<dim3(768 / 128, M / 128), 256, 0, stream>>>(qkvb, W2T, bfc2, x1, out, M, 768, 3072);
}

// Round 2
// 380.569 us; speedup vs baseline: 1.1881x; 1.1881x over previous
//
#include <hip/hip_runtime.h>
#include <hip/hip_bf16.h>
#include <stdint.h>
#include <string.h>

#define D_MODEL 768
#define H_HEADS 12
#define HD_ 64
#define N_QKV 2304

typedef __bf16 bf16x8 __attribute__((ext_vector_type(8)));
typedef float f32x4 __attribute__((ext_vector_type(4)));

__device__ __forceinline__ void gload16(const void* gsrc, void* ldst) {
  __builtin_amdgcn_global_load_lds(
      (__attribute__((address_space(1))) void*)gsrc,
      (__attribute__((address_space(3))) void*)ldst, 16, 0, 0);
}

__device__ __forceinline__ unsigned short f2bfbits(float f) {
  union { float f; unsigned u; } x; x.f = f;
  unsigned r = x.u + 0x7fffu + ((x.u >> 16) & 1u);
  return (unsigned short)(r >> 16);
}

// pack two non-negative floats to bf16 pair (round-to-nearest-ish)
__device__ __forceinline__ unsigned pk2(float a, float b) {
  union { float f; unsigned u; } x, y; x.f = a; y.f = b;
  return ((x.u + 0x8000u) >> 16) | ((y.u + 0x8000u) & 0xffff0000u);
}

__device__ __forceinline__ f32x4 vmax4(f32x4 a, f32x4 b) {
  f32x4 r;
  r[0] = fmaxf(a[0], b[0]); r[1] = fmaxf(a[1], b[1]);
  r[2] = fmaxf(a[2], b[2]); r[3] = fmaxf(a[3], b[3]);
  return r;
}

// ---------------- weight transpose + fp32->bf16 ----------------
__global__ void transpose_w(const float* __restrict__ in, unsigned short* __restrict__ out,
                            int R, int C) {
  __shared__ float tile[32][33];
  int c0 = blockIdx.x * 32, r0 = blockIdx.y * 32;
  int tx = threadIdx.x, ty = threadIdx.y;
#pragma unroll
  for (int i = 0; i < 32; i += 8)
    tile[ty + i][tx] = in[(size_t)(r0 + ty + i) * C + c0 + tx];
  __syncthreads();
#pragma unroll
  for (int i = 0; i < 32; i += 8)
    out[(size_t)(c0 + ty + i) * R + r0 + tx] = f2bfbits(tile[tx][ty + i]);
}

// ---------------- V transpose (bf16 -> bf16) with per-64-token key permute ----
// in: qkv [M][2304], V slice cols 1536..2303. out: vT [768][M], where within each
// aligned 64-token block, token at in-block pos c is stored at permuted col
// k(c) = 32*(c>>5) | 8*((c>>2)&3) | 4*((c>>4)&1) | (c&3)  (matches MFMA A-frag slots)
__global__ void transpose_v(const unsigned short* __restrict__ qkv,
                            unsigned short* __restrict__ vT, int M) {
  __shared__ unsigned short tile[32][33];
  int t0 = blockIdx.x * 32, c0 = blockIdx.y * 32;
  int tx = threadIdx.x, ty = threadIdx.y;
#pragma unroll
  for (int i = 0; i < 32; i += 8)
    tile[ty + i][tx] = qkv[(size_t)(t0 + ty + i) * N_QKV + 1536 + c0 + tx];
  __syncthreads();
  int t = t0 + tx;
  int c = t & 63;
  int kp = ((c >> 5) << 5) | (((c >> 2) & 3) << 3) | (((c >> 4) & 1) << 2) | (c & 3);
  size_t col = (size_t)(t & ~63) + kp;
#pragma unroll
  for (int i = 0; i < 32; i += 8)
    vT[(size_t)(c0 + ty + i) * M + col] = tile[tx][ty + i];
}

// ---------------- layernorm -> bf16 ----------------
__global__ void ln_bf16(const float* __restrict__ x, const float* __restrict__ g,
                        const float* __restrict__ be, unsigned short* __restrict__ out) {
  int row = blockIdx.x;
  const float* xr = x + (size_t)row * D_MODEL;
  int t = threadIdx.x;
  float v0 = xr[t], v1 = xr[t + 256], v2 = xr[t + 512];
  float s = v0 + v1 + v2;
  float s2 = v0 * v0 + v1 * v1 + v2 * v2;
#pragma unroll
  for (int off = 32; off > 0; off >>= 1) {
    s += __shfl_down(s, off, 64);
    s2 += __shfl_down(s2, off, 64);
  }
  __shared__ float red[8];
  int w = t >> 6, lane = t & 63;
  if (lane == 0) { red[w] = s; red[w + 4] = s2; }
  __syncthreads();
  if (t == 0) {
    float a = red[0] + red[1] + red[2] + red[3];
    float b = red[4] + red[5] + red[6] + red[7];
    red[0] = a * (1.0f / 768.0f);
    red[4] = b * (1.0f / 768.0f);
  }
  __syncthreads();
  float mu = red[0];
  float var = red[4] - mu * mu;
  float rs = rsqrtf(var + 1e-6f);
  unsigned short* orow = out + (size_t)row * D_MODEL;
  orow[t]       = f2bfbits((v0 - mu) * rs * g[t]       + be[t]);
  orow[t + 256] = f2bfbits((v1 - mu) * rs * g[t + 256] + be[t + 256]);
  orow[t + 512] = f2bfbits((v2 - mu) * rs * g[t + 512] + be[t + 512]);
}

// ---------------- m97-style bf16 MFMA GEMM, B^T input ----------------
template <int EPI>
__global__ void gemm_bt(const unsigned short* __restrict__ A,
                        const unsigned short* __restrict__ Bt,
                        const float* __restrict__ bias,
                        const float* __restrict__ res,
                        void* __restrict__ outv,
                        int M, int N, int K) {
  __shared__ unsigned short lA[128 * 32];
  __shared__ unsigned short lB[128 * 32];
  int tid = threadIdx.x;
  int w = tid >> 6, lane = tid & 63;
  int m0 = blockIdx.y * 128, n0 = blockIdx.x * 128;
  int wm = (w >> 1) * 64, wn = (w & 1) * 64;
  f32x4 acc[4][4];
#pragma unroll
  for (int i = 0; i < 4; i++)
#pragma unroll
    for (int j = 0; j < 4; j++) acc[i][j] = (f32x4){0.f, 0.f, 0.f, 0.f};

  int srow = tid >> 2, scol = (tid & 3) * 8;
  const unsigned short* gA0 = A + (size_t)(m0 + srow) * K + scol;
  const unsigned short* gB0 = Bt + (size_t)(n0 + srow) * K + scol;
  char* lA0 = (char*)lA + tid * 16;
  char* lB0 = (char*)lB + tid * 16;
  int fm = lane & 15, fk = (lane >> 4) * 8;

  for (int k0 = 0; k0 < K; k0 += 32) {
    __syncthreads();
    gload16(gA0 + k0, lA0);
    gload16(gA0 + (size_t)64 * K + k0, lA0 + 4096);
    gload16(gB0 + k0, lB0);
    gload16(gB0 + (size_t)64 * K + k0, lB0 + 4096);
    __syncthreads();
    bf16x8 af[4], bfr[4];
#pragma unroll
    for (int i = 0; i < 4; i++)
      af[i] = *(const bf16x8*)&lA[(wm + i * 16 + fm) * 32 + fk];
#pragma unroll
    for (int j = 0; j < 4; j++)
      bfr[j] = *(const bf16x8*)&lB[(wn + j * 16 + fm) * 32 + fk];
#pragma unroll
    for (int i = 0; i < 4; i++)
#pragma unroll
      for (int j = 0; j < 4; j++)
        acc[i][j] = __builtin_amdgcn_mfma_f32_16x16x32_bf16(af[i], bfr[j], acc[i][j], 0, 0, 0);
  }

  int er = (lane >> 4) * 4, ec = lane & 15;
#pragma unroll
  for (int i = 0; i < 4; i++) {
#pragma unroll
    for (int j = 0; j < 4; j++) {
      int n = n0 + wn + j * 16 + ec;
      float bv = bias[n];
#pragma unroll
      for (int r = 0; r < 4; r++) {
        int m = m0 + wm + i * 16 + er + r;
        float v = acc[i][j][r] + bv;
        if (EPI == 1) {
          v += res[(size_t)m * N + n];
          ((float*)outv)[(size_t)m * N + n] = v;
        } else {
          if (EPI == 2) v = 0.5f * v * (1.0f + erff(v * 0.70710678118f));
          ((unsigned short*)outv)[(size_t)m * N + n] = f2bfbits(v);
        }
      }
    }
  }
}

// ---------------- ragged flash attention v2 (S^T trick, zero-LDS P) ----------
// grid: B*H*(S_MAX/128); block 256 = 4 waves; wave w: 32 q rows [qc*128+w*32).
// S^T = K·Q^T per 16x16 tile -> lane holds q=lane&15, keys in regs; with the
// key permutation baked into vT, PV A-frag = lane's own packed exp values.
__global__ void attn_flash2(const unsigned short* __restrict__ qkv,
                            const unsigned short* __restrict__ vT,
                            const int* __restrict__ cu,
                            unsigned short* __restrict__ out, int M) {
  int qc = blockIdx.x & 7;
  int h = (blockIdx.x >> 3) % H_HEADS;
  int b = blockIdx.x / (8 * H_HEADS);
  int tok0 = cu[b];
  int len = cu[b + 1] - tok0;
  if (qc * 128 >= len) return;

  __shared__ unsigned short lK[64 * 64];   // [key][d], chunk-swizzled
  __shared__ unsigned short lVT[64 * 64];  // [d][permuted key], chunk-swizzled

  int tid = threadIdx.x, w = tid >> 6, lane = tid & 63;
  int fm = lane & 15, fg = lane >> 4;
  int xm = fm & 7;
  int qbase = qc * 128 + w * 32;

  bf16x8 qf[2][2];
#pragma unroll
  for (int qs = 0; qs < 2; qs++)
#pragma unroll
    for (int kh = 0; kh < 2; kh++)
      qf[qs][kh] = *(const bf16x8*)(qkv + (size_t)(tok0 + qbase + qs * 16 + fm) * N_QKV +
                                    h * 64 + kh * 32 + fg * 8);

  f32x4 Oacc[2][4];
#pragma unroll
  for (int qs = 0; qs < 2; qs++)
#pragma unroll
    for (int dt = 0; dt < 4; dt++) Oacc[qs][dt] = (f32x4){0.f, 0.f, 0.f, 0.f};
  float mrow[2] = {-1e30f, -1e30f}, lrow[2] = {0.f, 0.f};
  const float C2 = 0.18033688011112042f;  // log2(e)/sqrt(64)

  // staging: thread covers phys (row = tid>>3 (+32), chunk = tid&7); source
  // logical chunk = phys ^ (row&7)  -> readers XOR the same way (bank spread)
  int sr = tid >> 3, sp = tid & 7, sl = sp ^ (sr & 7);
  const unsigned short* kg0 = qkv + D_MODEL + h * 64 + sl * 8;
  const unsigned short* vg0 = vT + (size_t)(h * 64 + sr) * M + tok0 + sl * 8;
  char* lK0 = (char*)lK + tid * 16;
  char* lV0 = (char*)lVT + tid * 16;

  for (int kt = 0; kt < len; kt += 64) {
    __syncthreads();
    gload16(kg0 + (size_t)(tok0 + kt + sr) * N_QKV, lK0);
    gload16(kg0 + (size_t)(tok0 + kt + sr + 32) * N_QKV, lK0 + 4096);
    gload16(vg0 + kt, lV0);
    gload16(vg0 + (size_t)32 * M + kt, lV0 + 4096);
    __syncthreads();

    // ---- S^T tiles: s[qs][t], lane holds q=fm, key = kt + t*16 + fg*4 + r
    f32x4 s[2][4];
#pragma unroll
    for (int qs = 0; qs < 2; qs++)
#pragma unroll
      for (int t = 0; t < 4; t++) s[qs][t] = (f32x4){0.f, 0.f, 0.f, 0.f};
#pragma unroll
    for (int t = 0; t < 4; t++) {
      bf16x8 kf0 = *(const bf16x8*)&lK[(t * 16 + fm) * 64 + ((fg ^ xm) * 8)];
      bf16x8 kf1 = *(const bf16x8*)&lK[(t * 16 + fm) * 64 + (((4 + fg) ^ xm) * 8)];
#pragma unroll
      for (int qs = 0; qs < 2; qs++) {
        s[qs][t] = __builtin_amdgcn_mfma_f32_16x16x32_bf16(kf0, qf[qs][0], s[qs][t], 0, 0, 0);
        s[qs][t] = __builtin_amdgcn_mfma_f32_16x16x32_bf16(kf1, qf[qs][1], s[qs][t], 0, 0, 0);
      }
    }

    // ---- online softmax (row = fm; reduce across fg groups only)
    unsigned pkv[2][4][2];
#pragma unroll
    for (int qs = 0; qs < 2; qs++) {
      f32x4 m4 = vmax4(vmax4(s[qs][0], s[qs][1]), vmax4(s[qs][2], s[qs][3]));
      float mx = fmaxf(fmaxf(m4[0], m4[1]), fmaxf(m4[2], m4[3]));
      mx = fmaxf(mx, __shfl_xor(mx, 16, 64));
      mx = fmaxf(mx, __shfl_xor(mx, 32, 64));
      float mnew = fmaxf(mrow[qs], mx);
      float al = exp2f((mrow[qs] - mnew) * C2);
      mrow[qs] = mnew;
      float nm = mnew * C2;
      float ssum = 0.f;
#pragma unroll
      for (int t = 0; t < 4; t++) {
#pragma unroll
        for (int r = 0; r < 4; r++) {
          float p = exp2f(s[qs][t][r] * C2 - nm);
          s[qs][t][r] = p;
          ssum += p;
        }
        pkv[qs][t][0] = pk2(s[qs][t][0], s[qs][t][1]);
        pkv[qs][t][1] = pk2(s[qs][t][2], s[qs][t][3]);
      }
      ssum += __shfl_xor(ssum, 16, 64);
      ssum += __shfl_xor(ssum, 32, 64);
      lrow[qs] = lrow[qs] * al + ssum;
      // alpha to O-layout (O rows per lane are q_local = fg*4+r)
      float ar[4];
#pragma unroll
      for (int r = 0; r < 4; r++) ar[r] = __shfl(al, fg * 4 + r, 64);
#pragma unroll
      for (int dt = 0; dt < 4; dt++) {
        Oacc[qs][dt][0] *= ar[0]; Oacc[qs][dt][1] *= ar[1];
        Oacc[qs][dt][2] *= ar[2]; Oacc[qs][dt][3] *= ar[3];
      }
    }

    // ---- PV: A-frag is the lane's own packed p (key permutation handles layout)
    union { bf16x8 v; unsigned u[4]; } af[2][2];
#pragma unroll
    for (int qs = 0; qs < 2; qs++) {
      af[qs][0].u[0] = pkv[qs][0][0]; af[qs][0].u[1] = pkv[qs][0][1];
      af[qs][0].u[2] = pkv[qs][1][0]; af[qs][0].u[3] = pkv[qs][1][1];
      af[qs][1].u[0] = pkv[qs][2][0]; af[qs][1].u[1] = pkv[qs][2][1];
      af[qs][1].u[2] = pkv[qs][3][0]; af[qs][1].u[3] = pkv[qs][3][1];
    }
#pragma unroll
    for (int dt = 0; dt < 4; dt++) {
      bf16x8 vf0 = *(const bf16x8*)&lVT[(dt * 16 + fm) * 64 + ((fg ^ xm) * 8)];
      bf16x8 vf1 = *(const bf16x8*)&lVT[(dt * 16 + fm) * 64 + (((4 + fg) ^ xm) * 8)];
#pragma unroll
      for (int qs = 0; qs < 2; qs++) {
        Oacc[qs][dt] = __builtin_amdgcn_mfma_f32_16x16x32_bf16(af[qs][0].v, vf0, Oacc[qs][dt], 0, 0, 0);
        Oacc[qs][dt] = __builtin_amdgcn_mfma_f32_16x16x32_bf16(af[qs][1].v, vf1, Oacc[qs][dt], 0, 0, 0);
      }
    }
  }

#pragma unroll
  for (int qs = 0; qs < 2; qs++) {
    float inv = 1.0f / lrow[qs];
    float ir[4];
#pragma unroll
    for (int r = 0; r < 4; r++) ir[r] = __shfl(inv, fg * 4 + r, 64);
#pragma unroll
    for (int dt = 0; dt < 4; dt++)
#pragma unroll
      for (int r = 0; r < 4; r++)
        out[(size_t)(tok0 + qbase + qs * 16 + fg * 4 + r) * D_MODEL + h * 64 + dt * 16 + fm] =
            f2bfbits(Oacc[qs][dt][r] * ir[r]);
  }
}

extern "C" void kernel_launch(void* const* d_in, const int* in_sizes, int n_in,
                              void* d_out, int out_size, void* d_ws, size_t ws_size,
                              hipStream_t stream) {
  const float* x    = (const float*)d_in[0];
  const int* cu     = (const int*)d_in[1];
  const float* g1   = (const float*)d_in[2];
  const float* be1  = (const float*)d_in[3];
  const float* Wqkv = (const float*)d_in[4];
  const float* bqkv = (const float*)d_in[5];
  const float* Wo   = (const float*)d_in[6];
  const float* bo   = (const float*)d_in[7];
  const float* g2   = (const float*)d_in[8];
  const float* be2  = (const float*)d_in[9];
  const float* W1   = (const float*)d_in[10];
  const float* bfc1 = (const float*)d_in[11];
  const float* W2   = (const float*)d_in[12];
  const float* bfc2 = (const float*)d_in[13];
  float* out = (float*)d_out;
  int M = in_sizes[0] / D_MODEL;  // 6144

  unsigned short* WqkvT = (unsigned short*)d_ws;                       // 2304x768
  unsigned short* WoT   = WqkvT + 2304 * 768;                          // 768x768
  unsigned short* W1T   = WoT + 768 * 768;                             // 3072x768
  unsigned short* W2T   = W1T + 3072 * 768;                            // 768x3072
  unsigned short* bufA  = W2T + 768 * 3072;                            // M x 768 bf16
  float* x1             = (float*)(bufA + (size_t)M * D_MODEL);        // M x 768 f32
  unsigned short* qkvb  = (unsigned short*)(x1 + (size_t)M * D_MODEL); // M x 2304 / M x 3072 bf16
  // vT (768 x M bf16 = 9.4MB) overlaps x1 (18.9MB f32): vT is dead before the
  // Wo-gemm (which writes x1) runs.
  unsigned short* vT = (unsigned short*)x1;

  dim3 b32(32, 8);
  transpose_w<<<dim3(2304 / 32, 768 / 32), b32, 0, stream>>>(Wqkv, WqkvT, 768, 2304);
  transpose_w<<<dim3(768 / 32, 768 / 32), b32, 0, stream>>>(Wo, WoT, 768, 768);
  transpose_w<<<dim3(3072 / 32, 768 / 32), b32, 0, stream>>>(W1, W1T, 768, 3072);
  transpose_w<<<dim3(768 / 32, 3072 / 32), b32, 0, stream>>>(W2, W2T, 3072, 768);

  ln_bf16<<<M, 256, 0, stream>>>(x, g1, be1, bufA);
  gemm_bt<0><<<dim3(2304 / 128, M / 128), 256, 0, stream>>>(bufA, WqkvT, bqkv, nullptr, qkvb, M, 2304, 768);
  transpose_v<<<dim3(M / 32, 768 / 32), b32, 0, stream>>>(qkvb, vT, M);
  attn_flash2<<<8 * H_HEADS * 8, 256, 0, stream>>>(qkvb, vT, cu, bufA, M);
  gemm_bt<1><<<dim3(768 / 128, M / 128), 256, 0, stream>>>(bufA, WoT, bo, x, x1, M, 768, 768);
  ln_bf16<<<M, 256, 0, stream>>>(x1, g2, be2, bufA);
  gemm_bt<2><<<dim3(3072 / 128, M / 128), 256, 0, stream>>>(bufA, W1T, bfc1, nullptr, qkvb, M, 3072, 768);
  gemm_bt<1><<<dim3(768 / 128, M / 128), 256, 0, stream>>>(qkvb, W2T, bfc2, x1, out, M, 768, 3072);
}